// Round 4
// baseline (22491.866 us; speedup 1.0000x reference)
//
#include <hip/hip_runtime.h>

// ---------------------------------------------------------------------------
// Hierarchical GRU predictor — persistent scan, 16 col-slices x 4 batches/wg.
// B=64, T=256, D_IN=256, H=512, A=128, DEPTH=4.
//
// Round-4 structure (from round-3 counters):
//  - weights transposed+packed: UcT[col][k] (1152x512), UhT[col][k] (512x512)
//  - grid (16 slices, 16 quads); wg (s,q) serves batches [4q,4q+4), owns
//    G1 cols [72s,72s+72) and h cols [32s,32s+32).  Each weight byte feeds
//    4 batches -> 4x less L2 streaming than round 3.
//  - XCD map: linear = s + 16q -> XCD = s%8: per-XCD weights = 2 slices
//    (~425 KB) -> L2-resident (round 3: 3.36 MB footprint thrashed).
//  - gates (pol/act/dm) computed REDUNDANTLY by every wg (deterministic)
//    -> no gate exchange; slice 0 writes the scalar outputs.
//  - sync flags padded: one 128B line per quad (round 3: 256 wgs on 2 lines).
//  - exchange (hbuf/G1buf) via relaxed-agent (UC) atomics as before.
//  - XWA chunk = 32 steps (ws 21.5 MB).
// ---------------------------------------------------------------------------

#define Bn   64
#define Tn   256
#define DIN  256
#define Hn   512
#define An   128
#define DEP  4
#define N3   1536
#define NC   1664   // N3 + A
#define NU   1152   // 2*H + A
#define TB   (Tn * Bn)
#define CH   32     // timesteps per chunk
#define SL   16     // column slices
#define THREADS 320
#define HS   520    // padded LDS row stride

typedef unsigned long long ull;

__device__ __forceinline__ float hsigf(float v) {
    return fminf(fmaxf(0.2f * v + 0.5f, 0.f), 1.f);
}
__device__ __forceinline__ float aloadf(const float* p) {
    return __hip_atomic_load(p, __ATOMIC_RELAXED, __HIP_MEMORY_SCOPE_AGENT);
}
__device__ __forceinline__ ull aloadu(const ull* p) {
    return __hip_atomic_load(p, __ATOMIC_RELAXED, __HIP_MEMORY_SCOPE_AGENT);
}
__device__ __forceinline__ void astoref(float* p, float v) {
    __hip_atomic_store(p, v, __ATOMIC_RELAXED, __HIP_MEMORY_SCOPE_AGENT);
}

// ---------------------------------------------------------------- pack / init
__global__ __launch_bounds__(256) void pack_w_k(const float* __restrict__ W,
                                                const float* __restrict__ Wa1,
                                                float* __restrict__ Wc) {
    int idx = blockIdx.x * 256 + threadIdx.x;
    if (idx >= Hn * NC) return;
    int k = idx / NC, c = idx % NC;
    Wc[idx] = (c < N3) ? W[(size_t)k * N3 + c] : Wa1[(size_t)k * An + (c - N3)];
}

// transposed recurrent weights: UcT[col*512+k] = Uc[k][col]; UhT[j*512+k] = Uh[k][j]
__global__ __launch_bounds__(256) void pack_t_k(const float* __restrict__ U,
                                                const float* __restrict__ Ua1,
                                                float* __restrict__ UcT,
                                                float* __restrict__ UhT) {
    int idx = blockIdx.x * 256 + threadIdx.x;
    if (idx >= (NU + Hn) * Hn) return;
    int col = idx >> 9, k = idx & 511;
    if (col < NU) {
        UcT[idx] = (col < 1024) ? U[(size_t)k * N3 + col]
                                : Ua1[(size_t)k * An + (col - 1024)];
    } else {
        int j = col - NU;
        UhT[(size_t)j * Hn + k] = U[(size_t)k * N3 + 1024 + j];
    }
}

__global__ __launch_bounds__(256) void init_misc_k(const float* __restrict__ bb,
                                                   const float* __restrict__ ba1,
                                                   float* __restrict__ bc,
                                                   const float* __restrict__ mask,
                                                   float* __restrict__ seos,
                                                   float* __restrict__ dmh0,
                                                   float* __restrict__ o_pih,
                                                   unsigned int* __restrict__ flags) {
    int idx = blockIdx.x * 256 + threadIdx.x;
    if (idx < NC) bc[idx] = (idx < N3) ? bb[idx] : ba1[idx - N3];
    if (idx < 2048) flags[idx] = 0u;
    if (idx < TB) {
        int t = idx / Bn, b = idx % Bn;
        float m0 = mask[(size_t)b * Tn + t];
        dmh0[idx] = m0;                       // dm_hist[0][t][b]
        float s = 0.f;                        // seos[t] = eos[t-1]
        if (t > 0) s = mask[(size_t)b * Tn + (t - 1)] * (1.f - m0);
        seos[idx] = s;
    }
    if (idx < Bn * DEP * Hn) {                // pih[:, :, 0, :] = 0
        int b = idx / (DEP * Hn);
        int r = idx % (DEP * Hn);
        int d = r / Hn, h = r % Hn;
        o_pih[(((size_t)b * DEP + d) * Tn + 0) * Hn + h] = 0.f;
    }
}

// ------------------------------------------------------------ 64x64 tile GEMM
__global__ __launch_bounds__(256) void gemm64_k(
    const float* __restrict__ Am, long aBase0, long aStep, long aStride,
    const float* __restrict__ Bm, int ldb, const float* __restrict__ bias,
    float* __restrict__ Cm, long cBase0, long cStep, long cStride, int K) {
    const int qm = blockIdx.x, qn = blockIdx.y;
    const long aBase = aBase0 + (long)qm * aStep;
    const long cBase = cBase0 + (long)qm * cStep;
    const int n0 = qn * 64;
    __shared__ float As[64][65];
    __shared__ float Bs[64][68];
    const int tid = threadIdx.x;
    const int tx = tid & 15, ty = tid >> 4;
    float acc[4][4] = {};
    for (int k0 = 0; k0 < K; k0 += 64) {
#pragma unroll
        for (int fi = 0; fi < 4; ++fi) {
            const int f = fi * 256 + tid;
            const int mm = f >> 4;
            const int k4 = (f & 15) << 2;
            const float4 v = *(const float4*)(Am + aBase + (long)mm * aStride + k0 + k4);
            As[k4 + 0][mm] = v.x; As[k4 + 1][mm] = v.y;
            As[k4 + 2][mm] = v.z; As[k4 + 3][mm] = v.w;
        }
#pragma unroll
        for (int fi = 0; fi < 4; ++fi) {
            const int f = fi * 256 + tid;
            const int k = f >> 4;
            const int n4 = (f & 15) << 2;
            *(float4*)&Bs[k][n4] = *(const float4*)(Bm + (long)(k0 + k) * ldb + n0 + n4);
        }
        __syncthreads();
#pragma unroll 16
        for (int k = 0; k < 64; ++k) {
            const float a0 = As[k][ty * 4 + 0];
            const float a1 = As[k][ty * 4 + 1];
            const float a2 = As[k][ty * 4 + 2];
            const float a3 = As[k][ty * 4 + 3];
            const float4 bv = *(const float4*)&Bs[k][tx * 4];
            acc[0][0] = fmaf(a0, bv.x, acc[0][0]); acc[0][1] = fmaf(a0, bv.y, acc[0][1]);
            acc[0][2] = fmaf(a0, bv.z, acc[0][2]); acc[0][3] = fmaf(a0, bv.w, acc[0][3]);
            acc[1][0] = fmaf(a1, bv.x, acc[1][0]); acc[1][1] = fmaf(a1, bv.y, acc[1][1]);
            acc[1][2] = fmaf(a1, bv.z, acc[1][2]); acc[1][3] = fmaf(a1, bv.w, acc[1][3]);
            acc[2][0] = fmaf(a2, bv.x, acc[2][0]); acc[2][1] = fmaf(a2, bv.y, acc[2][1]);
            acc[2][2] = fmaf(a2, bv.z, acc[2][2]); acc[2][3] = fmaf(a2, bv.w, acc[2][3]);
            acc[3][0] = fmaf(a3, bv.x, acc[3][0]); acc[3][1] = fmaf(a3, bv.y, acc[3][1]);
            acc[3][2] = fmaf(a3, bv.z, acc[3][2]); acc[3][3] = fmaf(a3, bv.w, acc[3][3]);
        }
        __syncthreads();
    }
#pragma unroll
    for (int i = 0; i < 4; ++i) {
        const int mm = ty * 4 + i;
        float* cp = Cm + cBase + (long)mm * cStride + n0 + tx * 4;
#pragma unroll
        for (int j = 0; j < 4; ++j) {
            float v = acc[i][j];
            if (bias) v += bias[n0 + tx * 4 + j];
            cp[j] = v;
        }
    }
}

// ---------------------------------------------------- persistent scan (chunk)
__global__ __launch_bounds__(THREADS) void scan_chunk_k(
    const float* __restrict__ XWA, const float* __restrict__ UcT,
    const float* __restrict__ UhT, const float* __restrict__ W2,
    const float* __restrict__ b2,
    float* __restrict__ hbuf,            // [2][B][H]
    float* __restrict__ G1buf,           // [B][NU]
    unsigned int* __restrict__ flags,    // [2][16 quads][64-pad]
    const float* __restrict__ seos, float* __restrict__ dmh,
    float* __restrict__ acth,
    float* __restrict__ o_act, float* __restrict__ o_ac, float* __restrict__ o_pol,
    float* __restrict__ o_pix, float* __restrict__ o_pih, float* __restrict__ o_out,
    int d, int c) {
    const int s = blockIdx.x;            // slice (XCD = s%8: weights local)
    const int q = blockIdx.y;            // batch quad
    const int B0 = q * 4;
    const int tid = threadIdx.x;
    const int wv = tid >> 6, ln = tid & 63;
    const int llm = (d == DEP - 1) ? 1 : 0;

    __shared__ float h_s[4][HS];
    __shared__ float rh_s[4][HS];
    __shared__ float gate_s[4][4];       // both, h_only, x_only, dmp
    __shared__ float pa_s[4][2];         // prev act_out, prev dm_new (persist)
    __shared__ float w2_s[2 * An];
    __shared__ float b2_s[2];

    unsigned int* f1 = flags + q * 64;
    unsigned int* f2 = flags + 1024 + q * 64;

    // one-time per-launch LDS constants + prev-state restore
    for (int i = tid; i < 2 * An; i += THREADS) w2_s[i] = W2[i];
    if (tid < 2) b2_s[tid] = b2[tid];
    if (tid < 4) {
        float ap_ = 0.f, dp_ = 0.f;
        if (c > 0) {
            const int t0 = c * CH;
            ap_ = acth[(t0 - 1) * Bn + B0 + tid];
            dp_ = dmh[(size_t)(d + 1) * TB + (t0 - 1) * Bn + B0 + tid];
        }
        pa_s[tid][0] = ap_; pa_s[tid][1] = dp_;
    }
    __syncthreads();

    for (int tt = 0; tt < CH; ++tt) {
        const int t = c * CH + tt;
        const int g = d * Tn + t;
        const int par = g & 1;
        const unsigned int tgt = 16u * (unsigned)(g + 1);

        // early per-batch scalar loads for gates (wave wv = batch, lane 0)
        float dmp = 0.f, dmp1 = 1.f, ap = 0.f, eos1 = 0.f;
        if (wv < 4 && ln == 0) {
            const int gb = B0 + wv;
            dmp = dmh[(size_t)d * TB + t * Bn + gb];
            if (t > 0) dmp1 = dmh[(size_t)d * TB + (t - 1) * Bn + gb];
            if (d > 0) ap = o_act[(size_t)gb * DEP * Tn + (d - 1) * Tn + t];
            eos1 = seos[t * Bn + gb];
        }

        // ---- h(t) into LDS (UC 8B loads; written by all slices last step)
        if (t == 0) {
            for (int idx = tid; idx < 4 * Hn; idx += THREADS)
                h_s[idx >> 9][idx & 511] = 0.f;
        } else {
            for (int idx = tid; idx < 4 * (Hn / 2); idx += THREADS) {
                const int b = idx >> 8, kk = (idx & 255) * 2;
                const ull v = aloadu((const ull*)&hbuf[((size_t)par * Bn + B0 + b) * Hn + kk]);
                h_s[b][kk]     = __uint_as_float((unsigned)v);
                h_s[b][kk + 1] = __uint_as_float((unsigned)(v >> 32));
            }
        }
        __syncthreads();

        // ---- phase1: G1 cols [72s,72s+72) x 4 batches (288 dot-512)
        if (tid < 288) {
            const int c1 = tid >> 2, b = tid & 3;
            const int gcol = s * 72 + c1;
            const float* wp = UcT + (size_t)gcol * Hn;
            float4 a4 = {0.f, 0.f, 0.f, 0.f};
#pragma unroll 8
            for (int k4 = 0; k4 < Hn; k4 += 4) {
                const float4 w = *(const float4*)(wp + k4);
                const float4 h = *(const float4*)&h_s[b][k4];
                a4.x = fmaf(w.x, h.x, a4.x); a4.y = fmaf(w.y, h.y, a4.y);
                a4.z = fmaf(w.z, h.z, a4.z); a4.w = fmaf(w.w, h.w, a4.w);
            }
            astoref(&G1buf[(size_t)(B0 + b) * NU + gcol],
                    (a4.x + a4.y) + (a4.z + a4.w));
        }

        // ---- sync1: all slices' G1 at coherence point
        __syncthreads();
        if (tid == 0) {
            __hip_atomic_fetch_add(f1, 1u, __ATOMIC_RELAXED, __HIP_MEMORY_SCOPE_AGENT);
            while (__hip_atomic_load(f1, __ATOMIC_RELAXED, __HIP_MEMORY_SCOPE_AGENT) < tgt)
                __builtin_amdgcn_s_sleep(1);
        }
        __syncthreads();

        // ---- gates: redundant per wg; wave wv = batch wv (lanes = A cols)
        if (wv < 4) {
            const int gb = B0 + wv;
            const float* xr = XWA + ((size_t)tt * Bn + gb) * NC;
            const float g0 = aloadf(&G1buf[(size_t)gb * NU + 1024 + ln]);
            const float g1 = aloadf(&G1buf[(size_t)gb * NU + 1024 + 64 + ln]);
            const float ph0 = fmaxf(xr[N3 + ln] + g0, 0.f);
            const float ph1 = fmaxf(xr[N3 + 64 + ln] + g1, 0.f);
            float p0p = ph0 * w2_s[2 * ln]     + ph1 * w2_s[2 * (64 + ln)];
            float p1p = ph0 * w2_s[2 * ln + 1] + ph1 * w2_s[2 * (64 + ln) + 1];
            for (int off = 32; off; off >>= 1) {
                p0p += __shfl_down(p0p, off);
                p1p += __shfl_down(p1p, off);
            }
            if (ln == 0) {
                const float p0 = expf(b2_s[0] + p0p), p1 = expf(b2_s[1] + p1p);
                const float a_tm1   = (t == 0) ? 0.f : pa_s[wv][0];
                const float dmc_tm1 = (t == 0) ? 0.f : pa_s[wv][1];
                float act = (p0 >= p1) ? 1.f : 0.f;
                if (ap > 0.f) act = 1.f;
                if (llm) act = 1.f;
                if (eos1 > 0.f) act = 0.f;
                const float lf = llm ? 1.f : 0.f;
                const float acalc  = dmp1 * (1.f - lf) * (1.f - eos1) * (1.f - ap);
                const float both   = (1.f - ap) * dmp * act * dmc_tm1;
                const float h_only = dmc_tm1 * act * (ap + (1.f - ap) * (1.f - dmp));
                const float x_only = dmp * (1.f - ap) * (1.f - act + act * (1.f - dmc_tm1));
                const float dm_new = dmp * (both + x_only + h_only);
                const float act_out = (dmp1 > 0.f) ? act : a_tm1;
                gate_s[wv][0] = both; gate_s[wv][1] = h_only;
                gate_s[wv][2] = x_only; gate_s[wv][3] = dmp;
                pa_s[wv][0] = act_out; pa_s[wv][1] = dm_new;
                if (s == 0) {   // one slice writes scalar outputs
                    acth[t * Bn + gb] = act_out;
                    dmh[(size_t)(d + 1) * TB + t * Bn + gb] = dm_new;
                    o_ac[(size_t)gb * DEP * Tn + d * Tn + t] = acalc;
                    o_pol[((size_t)gb * DEP * Tn + d * Tn + t) * 2 + 0] = p0;
                    o_pol[((size_t)gb * DEP * Tn + d * Tn + t) * 2 + 1] = p1;
                    if (t > 0) o_act[(size_t)gb * DEP * Tn + d * Tn + (t - 1)] = act_out;
                    if (t == Tn - 1) o_act[(size_t)gb * DEP * Tn + d * Tn + (Tn - 1)] = 0.f;
                }
            }
        }

        // ---- rh = hsig(xr + G1r) * h, full 512 x 4 batches (UC 8B loads)
        for (int idx = tid; idx < 4 * (Hn / 2); idx += THREADS) {
            const int b = idx >> 8, kk = (idx & 255) * 2;
            const int gb = B0 + b;
            const ull gv = aloadu((const ull*)&G1buf[(size_t)gb * NU + 512 + kk]);
            const float* xr = XWA + ((size_t)tt * Bn + gb) * NC + 512 + kk;
            const float r0 = hsigf(xr[0] + __uint_as_float((unsigned)gv));
            const float r1 = hsigf(xr[1] + __uint_as_float((unsigned)(gv >> 32)));
            rh_s[b][kk]     = r0 * h_s[b][kk];
            rh_s[b][kk + 1] = r1 * h_s[b][kk + 1];
        }
        __syncthreads();   // rh + gate_s ready

        // ---- phase2: h cols [32s,32s+32) x 4 batches
        if (tid < 128) {
            const int c2 = tid >> 2, b = tid & 3;
            const int gj = s * 32 + c2;
            const int gb = B0 + b;
            const float* xr = XWA + ((size_t)tt * Bn + gb) * NC;
            const float zg = aloadf(&G1buf[(size_t)gb * NU + gj]);
            const float xt = o_pix[(((size_t)gb * DEP + d) * Tn + t) * Hn + gj];
            const float* wp = UhT + (size_t)gj * Hn;
            float4 a4 = {0.f, 0.f, 0.f, 0.f};
#pragma unroll 8
            for (int k4 = 0; k4 < Hn; k4 += 4) {
                const float4 w = *(const float4*)(wp + k4);
                const float4 r = *(const float4*)&rh_s[b][k4];
                a4.x = fmaf(w.x, r.x, a4.x); a4.y = fmaf(w.y, r.y, a4.y);
                a4.z = fmaf(w.z, r.z, a4.z); a4.w = fmaf(w.w, r.w, a4.w);
            }
            const float dot = (a4.x + a4.y) + (a4.z + a4.w);
            const float z = hsigf(xr[gj] + zg);
            const float hp = h_s[b][gj];
            const float th = tanhf(xr[1024 + gj] + dot);
            const float hc = z * hp + (1.f - z) * th;
            const float both = gate_s[b][0], h_only = gate_s[b][1],
                        x_only = gate_s[b][2], dmpv = gate_s[b][3];
            float hv = (both > 0.f) ? hc : 0.f;
            if (h_only > 0.f) hv = hp;
            if (x_only > 0.f) hv = xt;
            if (!(dmpv > 0.f)) hv = hp;
            astoref(&hbuf[((size_t)(par ^ 1) * Bn + gb) * Hn + gj], hv);
            if (d < DEP - 1) o_pix[(((size_t)gb * DEP + d + 1) * Tn + t) * Hn + gj] = hv;
            if (t > 0)       o_pih[(((size_t)gb * DEP + d) * Tn + t) * Hn + gj] = hv;
            if (d == DEP - 1 && t == Tn - 1) o_out[(size_t)gb * Hn + gj] = hv;
        }

        // ---- sync2: h(t+1) complete
        __syncthreads();
        if (tid == 0) {
            __hip_atomic_fetch_add(f2, 1u, __ATOMIC_RELAXED, __HIP_MEMORY_SCOPE_AGENT);
            while (__hip_atomic_load(f2, __ATOMIC_RELAXED, __HIP_MEMORY_SCOPE_AGENT) < tgt)
                __builtin_amdgcn_s_sleep(1);
        }
        __syncthreads();
    }
}

// ---------------------------------------------------------------------------
extern "C" void kernel_launch(void* const* d_in, const int* in_sizes, int n_in,
                              void* d_out, int out_size, void* d_ws, size_t ws_size,
                              hipStream_t stream) {
    const float* x     = (const float*)d_in[0];
    const float* mask  = (const float*)d_in[1];
    const float* W_emb = (const float*)d_in[3];
    const float* b_emb = (const float*)d_in[4];
    const float* W     = (const float*)d_in[5];
    const float* U     = (const float*)d_in[6];
    const float* bb    = (const float*)d_in[7];
    const float* Wa1   = (const float*)d_in[8];
    const float* Ua1   = (const float*)d_in[9];
    const float* ba1   = (const float*)d_in[10];
    const float* W2    = (const float*)d_in[11];
    const float* b2    = (const float*)d_in[12];

    float* out = (float*)d_out;
    float* o_out = out;
    float* o_act = out + (size_t)Bn * Hn;
    float* o_ac  = o_act + (size_t)Bn * DEP * Tn;
    float* o_pix = o_ac + (size_t)Bn * DEP * Tn;
    float* o_pih = o_pix + (size_t)Bn * DEP * Tn * Hn;
    float* o_pol = o_pih + (size_t)Bn * DEP * Tn * Hn;

    float* ws      = (float*)d_ws;
    float* seos    = ws;                                  // 16384
    float* dmh     = seos + TB;                           // 5*16384
    float* acth    = dmh + (DEP + 1) * TB;                // 16384
    float* hbuf    = acth + TB;                           // 2*B*H
    float* G1buf   = hbuf + 2 * Bn * Hn;                  // B*NU
    unsigned int* flags = (unsigned int*)(G1buf + (size_t)Bn * NU);  // 2048 u32
    float* Wc      = (float*)(flags + 2048);              // H*NC
    float* bc      = Wc + (size_t)Hn * NC;                // NC
    float* UcT     = bc + NC;                             // NU*H
    float* UhT     = UcT + (size_t)NU * Hn;               // H*H
    float* XWA     = UhT + (size_t)Hn * Hn;               // CH*B*NC (~13.6 MB)

    pack_w_k<<<(Hn * NC + 255) / 256, 256, 0, stream>>>(W, Wa1, Wc);
    pack_t_k<<<((NU + Hn) * Hn + 255) / 256, 256, 0, stream>>>(U, Ua1, UcT, UhT);
    init_misc_k<<<(Bn * DEP * Hn + 255) / 256, 256, 0, stream>>>(
        bb, ba1, bc, mask, seos, dmh, o_pih, flags);

    // emb: pix[:,0] = x @ W_emb + b_emb
    gemm64_k<<<dim3(Tn, Hn / 64), 256, 0, stream>>>(
        x, 0L, (long)DIN, (long)Tn * DIN, W_emb, Hn, b_emb,
        o_pix, 0L, (long)Hn, (long)DEP * Tn * Hn, DIN);

    for (int d = 0; d < DEP; ++d) {
        for (int c = 0; c < Tn / CH; ++c) {
            gemm64_k<<<dim3(CH, NC / 64), 256, 0, stream>>>(
                o_pix, (long)(d * Tn + c * CH) * Hn, (long)Hn, (long)DEP * Tn * Hn,
                Wc, NC, bc, XWA, 0L, (long)Bn * NC, (long)NC, Hn);
            scan_chunk_k<<<dim3(SL, 16), THREADS, 0, stream>>>(
                XWA, UcT, UhT, W2, b2, hbuf, G1buf, flags,
                seos, dmh, acth, o_act, o_ac, o_pol, o_pix, o_pih, o_out, d, c);
        }
    }
}